// Round 18
// baseline (206.585 us; speedup 1.0000x reference)
//
#include <hip/hip_runtime.h>

// Problem constants
#define NB 8
#define NC 128
#define NH 64
#define NW 64
#define HEADS 4
#define HP 32
#define WP 32
#define NTOK 1024     // HP*WP
#define TOPK 32
#define HDIM 32

typedef __fp16 hh2 __attribute__((ext_vector_type(2)));

__device__ __forceinline__ hh2 h2cast(unsigned u) {
  union { unsigned u; hh2 h; } x; x.u = u; return x.h;
}
__device__ __forceinline__ unsigned pkf16(float a, float b) {
  union { hh2 h; unsigned u; } x; x.h = __builtin_amdgcn_cvt_pkrtz(a, b); return x.u;
}

#if __has_builtin(__builtin_amdgcn_fdot2)
__device__ __forceinline__ float fdot2(unsigned kw, unsigned qw, float c) {
  return __builtin_amdgcn_fdot2(h2cast(kw), h2cast(qw), c, false);
}
#else
__device__ __forceinline__ float fdot2(unsigned kw, unsigned qw, float c) {
  hh2 k = h2cast(kw), q = h2cast(qw);
  return fmaf((float)k.x, (float)q.x, fmaf((float)k.y, (float)q.y, c));
}
#endif

// monotone float->uint map (order-preserving) and inverse
__device__ __forceinline__ unsigned fmap(float f) {
  unsigned u = __float_as_uint(f);
  return u ^ ((unsigned)((int)u >> 31) | 0x80000000u);
}
__device__ __forceinline__ float funmap(unsigned k) {
  unsigned uo = k ^ ((unsigned)((int)(~k) >> 31) | 0x80000000u);
  return __uint_as_float(uo);
}

// DPP wave64 max-reduce on unsigned; result broadcast via readlane(63)
__device__ __forceinline__ unsigned wave_maxu(unsigned v) {
#define ST(ctrl)                                                                     \
  {                                                                                  \
    unsigned o = (unsigned)__builtin_amdgcn_update_dpp(0, (int)v, ctrl, 0xF, 0xF, true); \
    v = v > o ? v : o;                                                               \
  }
  ST(0xB1)   // quad_perm [1,0,3,2]
  ST(0x4E)   // quad_perm [2,3,0,1]
  ST(0x141)  // row_half_mirror
  ST(0x140)  // row_mirror
  ST(0x142)  // row_bcast:15
  ST(0x143)  // row_bcast:31
#undef ST
  return (unsigned)__builtin_amdgcn_readlane((int)v, 63);
}

// DPP wave64 float sum-reduce; result broadcast via readlane(63)
__device__ __forceinline__ float wave_sumf(float v) {
#define STA(ctrl)                                                                    \
  v += __int_as_float(__builtin_amdgcn_update_dpp(0, __float_as_int(v), ctrl, 0xF, 0xF, true));
  STA(0xB1)
  STA(0x4E)
  STA(0x141)
  STA(0x140)
  STA(0x142)
  STA(0x143)
#undef STA
  return __int_as_float(__builtin_amdgcn_readlane(__float_as_int(v), 63));
}

// DPP wave64 inclusive prefix-sum on unsigned. Safe for packed 16+16 fields.
__device__ __forceinline__ unsigned wave_iprefix(unsigned v, int lane) {
#define SH(ctrl)                                                                     \
  v += (unsigned)__builtin_amdgcn_update_dpp(0, (int)v, ctrl, 0xF, 0xF, true);
  SH(0x111)  // row_shr:1
  SH(0x112)  // row_shr:2
  SH(0x114)  // row_shr:4
  SH(0x118)  // row_shr:8
#undef SH
  unsigned r0 = (unsigned)__builtin_amdgcn_readlane((int)v, 15);
  unsigned r1 = (unsigned)__builtin_amdgcn_readlane((int)v, 31);
  unsigned r2 = (unsigned)__builtin_amdgcn_readlane((int)v, 47);
  v += (lane >= 16) ? r0 : 0u;
  v += (lane >= 32) ? r1 : 0u;
  v += (lane >= 48) ? r2 : 0u;
  return v;
}

// ---------------------------------------------------------------
// prep: avg-pool x,y -> f16 channel-pairs AND pack conv weights to f16 pairs.
__global__ void k_prep(const float* __restrict__ x, const float* __restrict__ y,
                       const float* __restrict__ q1w, const float* __restrict__ kv1w,
                       const float* __restrict__ outw,
                       unsigned* __restrict__ xph, unsigned* __restrict__ yph,
                       unsigned* __restrict__ wph) {
  int idx = blockIdx.x * 256 + threadIdx.x;
  const int total = NB * 64 * NTOK; // 524288 pairs per array
  if (idx < 2 * total) {
    bool isY = idx >= total;
    int i = isY ? idx - total : idx;
    int p = i & 1023;
    int pw = p & 31, ph = p >> 5;
    int bc2 = i >> 10;
    int c2 = bc2 & 63, b = bc2 >> 6;
    const float* s0 = (isY ? y : x) + (((size_t)b * NC + 2 * c2) * 64 + ph * 2) * 64 + pw * 2;
    const float* s1 = s0 + 4096;
    float v0 = 0.25f * (s0[0] + s0[1] + s0[64] + s0[65]);
    float v1 = 0.25f * (s1[0] + s1[1] + s1[64] + s1[65]);
    (isY ? yph : xph)[i] = pkf16(v0, v1);
  } else {
    int i = idx - 2 * total;
    if (i >= 32768) return;
    const float* src;
    int off;
    if (i < 8192) { src = q1w; off = i; }
    else if (i < 24576) { src = kv1w; off = i - 8192; }
    else { src = outw; off = i - 24576; }
    int co = off >> 6, ci2 = off & 63;
    wph[i] = pkf16(src[co * 128 + 2 * ci2], src[co * 128 + 2 * ci2 + 1]);
  }
}

// ---------------------------------------------------------------
// unified q/kv path: f16-dot2 1x1 conv (4 ch/thread) -> LDS tile -> 3x3
// (depthwise for q, grouped-2 for kv). grid = 8b x 96 units (32 q + 64 kv).
__launch_bounds__(1024, 2)
__global__ void k_qkv(const unsigned* __restrict__ xph, const unsigned* __restrict__ yph,
                      const unsigned* __restrict__ wph,
                      const float* __restrict__ q1b, const float* __restrict__ q2w,
                      const float* __restrict__ q2b,
                      const float* __restrict__ kv1b, const float* __restrict__ kv2w,
                      const float* __restrict__ kv2b,
                      unsigned* __restrict__ qh, unsigned* __restrict__ kpair,
                      unsigned short* __restrict__ vbf) {
  __shared__ float cls[4][1024];
  int px = threadIdx.x;
  int bid = blockIdx.x;
  int b = bid / 96;
  int u = bid - b * 96;
  bool isQ = u < 32;
  int q = isQ ? u : u - 32;

  const unsigned* ip = (isQ ? xph : yph) + (size_t)b * 64 * NTOK + px;
  const unsigned* wp = wph + (isQ ? 0 : 8192) + q * 4 * 64;
  const float* bb = isQ ? q1b : kv1b;
  float acc[4];
#pragma unroll
  for (int i = 0; i < 4; i++) acc[i] = bb[q * 4 + i];
  for (int ci2 = 0; ci2 < 64; ci2++) {
    unsigned mv = ip[ci2 * NTOK];
#pragma unroll
    for (int i = 0; i < 4; i++) acc[i] = fdot2(mv, wp[i * 64 + ci2], acc[i]);
  }
#pragma unroll
  for (int i = 0; i < 4; i++) cls[i][px] = acc[i];
  __syncthreads();
  int pw = px & 31, ph = px >> 5;

  if (isQ) {
    float aout[4];
#pragma unroll
    for (int i = 0; i < 4; i++) {
      int c = q * 4 + i;
      const float* wq = q2w + c * 9;
      float a = q2b[c];
#pragma unroll
      for (int ky = 0; ky < 3; ky++) {
        int ih = ph + ky - 1;
        if (ih < 0 || ih > 31) continue;
#pragma unroll
        for (int kx = 0; kx < 3; kx++) {
          int iw = pw + kx - 1;
          if (iw < 0 || iw > 31) continue;
          a = fmaf(wq[ky * 3 + kx], cls[i][ih * 32 + iw], a);
        }
      }
      aout[i] = a;
    }
    int h = q >> 3;
    int d2 = ((q * 4) & 31) >> 1;
    size_t base = (((size_t)b * HEADS + h) * NTOK + px) * 16;
    qh[base + d2] = pkf16(aout[0], aout[1]);
    qh[base + d2 + 1] = pkf16(aout[2], aout[3]);
  } else {
    float aout[4];
#pragma unroll
    for (int i = 0; i < 4; i++) {
      int o = q * 4 + i;       // kv channel 0..255
      int l0 = i & ~1;         // group's first input channel within the quad
      const float* wq = kv2w + o * 18; // [2][3][3]
      float a = kv2b[o];
#pragma unroll
      for (int ky = 0; ky < 3; ky++) {
        int ih = ph + ky - 1;
        if (ih < 0 || ih > 31) continue;
#pragma unroll
        for (int kx = 0; kx < 3; kx++) {
          int iw = pw + kx - 1;
          if (iw < 0 || iw > 31) continue;
          a = fmaf(wq[ky * 3 + kx], cls[l0][ih * 32 + iw], a);
          a = fmaf(wq[9 + ky * 3 + kx], cls[l0 + 1][ih * 32 + iw], a);
        }
      }
      aout[i] = a;
    }
    if (q < 32) {
      // K channels: quad = 4 consecutive d within head h
      int h = q >> 3;
      int d2 = ((q * 4) & 31) >> 1;
      size_t base = (((size_t)b * HEADS + h) * 16) * NTOK + px;
      kpair[base + (size_t)d2 * NTOK] = pkf16(aout[0], aout[1]);
      kpair[base + (size_t)(d2 + 1) * NTOK] = pkf16(aout[2], aout[3]);
    } else {
      // V channels
#pragma unroll
      for (int i = 0; i < 4; i++) {
        int c = q * 4 + i - 128;
        int h = c >> 5, d = c & 31;
        union { __fp16 h; unsigned short u; } cv;
        cv.h = (__fp16)aout[i];
        vbf[(((size_t)b * HEADS + h) * NTOK + px) * HDIM + d] = cv.u;
      }
    }
  }
}

// ---------------------------------------------------------------
// attention v12: K direct from L2 (no LDS staging), launch_bounds(512,2) so
// the allocator keeps ~64 VGPR (no spill); occupancy then HW-bound at
// 8 waves/SIMD. grid: 2048 = 64 chunks x 4 h x 8 b; block 512, 2 rows/wave.
__launch_bounds__(512, 2)
__global__ void k_attn(const unsigned* __restrict__ qh, const unsigned* __restrict__ kpair,
                       const unsigned short* __restrict__ vbf, const float* __restrict__ rel,
                       const float* __restrict__ temp, float* __restrict__ att) {
  __shared__ __align__(16) unsigned cbuf[8 * 64]; // per-wave 32x(key,token), 2KB

  int bid = blockIdx.x;
  int chunk = bid & 63;
  int h = (bid >> 6) & 3;
  int b = bid >> 8;
  int tid = threadIdx.x;
  int lane = tid & 63;
  int wave = __builtin_amdgcn_readfirstlane(tid >> 6); // 0..7, uniform

  const unsigned* kbase = kpair + ((size_t)b * HEADS + h) * 16 * NTOK;

  const float tmpr = temp[h];
  const unsigned short* vb = vbf + ((size_t)(b * HEADS + h)) * NTOK * HDIM;
  int vlane = lane & 31;
  unsigned* row_lds = cbuf + wave * 64; // 32 entries x 8B, private per wave

  int qbase = chunk * 16 + wave * 2;

  // load q pairs for both rows (wave-uniform broadcast loads)
  unsigned qp[2][16];
#pragma unroll
  for (int r = 0; r < 2; r++) {
    const uint4* q4 = (const uint4*)(qh + (((size_t)b * HEADS + h) * NTOK + qbase + r) * 16);
#pragma unroll
    for (int i = 0; i < 4; i++) {
      uint4 t = q4[i];
      qp[r][i * 4 + 0] = t.x;
      qp[r][i * 4 + 1] = t.y;
      qp[r][i * 4 + 2] = t.z;
      qp[r][i * 4 + 3] = t.w;
    }
  }

  // logits via f16 dot2 reading K straight from L2: coalesced uint4 per lane
  float acc[2][16];
#pragma unroll
  for (int r = 0; r < 2; r++)
#pragma unroll
    for (int e = 0; e < 16; e++) acc[r][e] = 0.f;

#pragma unroll 4
  for (int d2 = 0; d2 < 16; d2++) {
#pragma unroll
    for (int i = 0; i < 4; i++) {
      uint4 kw = *(const uint4*)&kbase[d2 * 1024 + i * 256 + lane * 4]; // tokens i*256+lane*4+m
      acc[0][i * 4 + 0] = fdot2(kw.x, qp[0][d2], acc[0][i * 4 + 0]);
      acc[0][i * 4 + 1] = fdot2(kw.y, qp[0][d2], acc[0][i * 4 + 1]);
      acc[0][i * 4 + 2] = fdot2(kw.z, qp[0][d2], acc[0][i * 4 + 2]);
      acc[0][i * 4 + 3] = fdot2(kw.w, qp[0][d2], acc[0][i * 4 + 3]);
      acc[1][i * 4 + 0] = fdot2(kw.x, qp[1][d2], acc[1][i * 4 + 0]);
      acc[1][i * 4 + 1] = fdot2(kw.y, qp[1][d2], acc[1][i * 4 + 1]);
      acc[1][i * 4 + 2] = fdot2(kw.z, qp[1][d2], acc[1][i * 4 + 2]);
      acc[1][i * 4 + 3] = fdot2(kw.w, qp[1][d2], acc[1][i * 4 + 3]);
    }
  }

  // pack keys, fusing rel
  const float4* relp = (const float4*)(rel + (((size_t)b * HEADS + h) * NTOK + qbase) * NTOK);
  unsigned kk[2][16];
#pragma unroll
  for (int r = 0; r < 2; r++) {
#pragma unroll
    for (int i = 0; i < 4; i++) {
      float4 rv = relp[r * 256 + i * 64 + lane];
      kk[r][i * 4 + 0] = fmap(fmaf(tmpr, acc[r][i * 4 + 0], rv.x));
      kk[r][i * 4 + 1] = fmap(fmaf(tmpr, acc[r][i * 4 + 1], rv.y));
      kk[r][i * 4 + 2] = fmap(fmaf(tmpr, acc[r][i * 4 + 2], rv.z));
      kk[r][i * 4 + 3] = fmap(fmaf(tmpr, acc[r][i * 4 + 3], rv.w));
    }
  }

  // wave max per row (bsearch upper bound + softmax max)
  unsigned M[2];
#pragma unroll
  for (int r = 0; r < 2; r++) {
    unsigned mx = kk[r][0];
#pragma unroll
    for (int e = 1; e < 16; e++) mx = mx > kk[r][e] ? mx : kk[r][e];
    M[r] = wave_maxu(mx);
  }

  // early-exit binary search; cap 32 -> exact-tie fallback
  unsigned lo0 = 0u, hi0 = M[0], lo1 = 0u, hi1 = M[1];
  unsigned T0x = 0u, T1x = 0u;
  bool d0 = false, d1 = false;
#pragma unroll 1
  for (int it = 0; it < 32; it++) {
    if (d0 && d1) break;
    if (!d0) {
      unsigned mid = lo0 + ((hi0 - lo0) >> 1);
      int c = 0;
#pragma unroll
      for (int e = 0; e < 16; e++) c += (int)__popcll(__ballot(kk[0][e] > mid));
      if (c >= TOPK) lo0 = mid; else hi0 = mid;
      if (c == TOPK) { T0x = mid; d0 = true; }
    }
    if (!d1) {
      unsigned mid = lo1 + ((hi1 - lo1) >> 1);
      int c = 0;
#pragma unroll
      for (int e = 0; e < 16; e++) c += (int)__popcll(__ballot(kk[1][e] > mid));
      if (c >= TOPK) lo1 = mid; else hi1 = mid;
      if (c == TOPK) { T1x = mid; d1 = true; }
    }
  }
  unsigned T[2];
  T[0] = d0 ? T0x : hi0;
  T[1] = d1 ? T1x : hi1;

  // per-row: tie handling, compaction, softmax + V gather
#pragma unroll
  for (int r = 0; r < 2; r++) {
    unsigned gtc = 0, tq = 0;
#pragma unroll
    for (int e = 0; e < 16; e++) {
      gtc += (kk[r][e] > T[r]) ? 1u : 0u;
      tq += (kk[r][e] == T[r]) ? 1u : 0u;
    }
    unsigned packed = gtc | (tq << 16);
    unsigned incl = wave_iprefix(packed, lane);
    unsigned tot = (unsigned)__builtin_amdgcn_readlane((int)incl, 63);
    unsigned n_gt = tot & 0xFFFFu;
    unsigned tie_pfx = (incl >> 16) - tq;
    unsigned extras = (unsigned)TOPK - n_gt; // 0 on early-exit rows
    int el = (int)extras - (int)tie_pfx;
    el = el < 0 ? 0 : el;
    el = el > (int)tq ? (int)tq : el;
    unsigned sc = gtc + (unsigned)el;
    unsigned wbase = wave_iprefix(sc, lane) - sc;

    unsigned wp = wbase, tr = tie_pfx;
#pragma unroll
    for (int e = 0; e < 16; e++) {
      bool gt = kk[r][e] > T[r];
      bool eq = (kk[r][e] == T[r]);
      bool take = gt || (eq && (tr < extras));
      tr += eq ? 1u : 0u;
      if (take) {
        ((uint2*)row_lds)[wp] = make_uint2(kk[r][e], (unsigned)((e >> 2) * 256 + lane * 4 + (e & 3)));
        wp++;
      }
    }

    // parallel softmax over the 32 entries (lanes 0..31) + pipelined V gather
    uint2 ent = ((const uint2*)row_lds)[vlane];
    float fv = funmap(ent.x);
    float mv = funmap(M[r]);
    float e_ = __expf(fv - mv);
    e_ = (lane < TOPK) ? e_ : 0.f;
    float se = wave_sumf(e_);

    float oacc = 0.f;
#pragma unroll
    for (int t = 0; t < TOPK; t++) {
      float es = __int_as_float(__builtin_amdgcn_readlane(__float_as_int(e_), t));
      int tok = __builtin_amdgcn_readlane((int)ent.y, t);
      union { unsigned short u; __fp16 h; } cv;
      cv.u = vb[(size_t)tok * HDIM + vlane];
      oacc = fmaf(es, (float)cv.h, oacc);
    }

    if (lane < HDIM) {
      att[((size_t)b * NC + h * HDIM + lane) * NTOK + (qbase + r)] = oacc / se;
    }
  }
}

// ---------------------------------------------------------------
// bilinear 2x upsample weights (jax scale_and_translate semantics)
__device__ __forceinline__ void bil(int i, int& j0, int& j1, float& wa, float& wb) {
  if (i & 1) {
    j0 = i >> 1; j1 = j0 + 1; wa = 0.75f; wb = 0.25f;
    if (j1 > 31) { j1 = 31; wa = 1.f; wb = 0.f; }
  } else {
    j0 = (i >> 1) - 1; j1 = j0 + 1; wa = 0.25f; wb = 0.75f;
    if (j0 < 0) { j0 = 0; wa = 0.f; wb = 1.f; }
  }
}

// ---------------------------------------------------------------
// fused mid+final: phase 1 computes lepe+upsample for all 128 channels of
// one 64-px output row into LDS (f16 pairs, padded [64][65]); phase 2 runs
// the final 1x1 conv (f16-dot2, scalar-hoisted weights) from LDS.
// grid: 512 = 8b x 64 rows; block 256.
__launch_bounds__(256, 4)
__global__ void k_midfinal(const float* __restrict__ x, const float* __restrict__ lepe_w,
                           const float* __restrict__ lepe_b, const float* __restrict__ attb,
                           const unsigned* __restrict__ wph, const float* __restrict__ outb,
                           float* __restrict__ out) {
  __shared__ unsigned mlds[64 * 65]; // [ci2][px], +1 pad -> 2-way banks (free)
  int bid = blockIdx.x;
  int h0 = bid & 63;
  int b = bid >> 6;
  int t = threadIdx.x;
  int ci2 = t >> 2;
  int w0 = (t & 3) * 16;

  int jh0, jh1;
  float wha, whb;
  bil(h0, jh0, jh1, wha, whb);

  float o0[16], o1[16];
#pragma unroll
  for (int cc = 0; cc < 2; cc++) {
    int c = 2 * ci2 + cc;
    const float* xp = x + ((size_t)b * NC + c) * 4096;
    const float* wq = lepe_w + c * 25;
    float* o = cc ? o1 : o0;
    float bv = lepe_b[c];
#pragma unroll
    for (int j = 0; j < 16; j++) o[j] = bv;
#pragma unroll
    for (int ky = 0; ky < 5; ky++) {
      int ih = h0 + ky - 2;
      if (ih < 0 || ih > 63) continue;
      float xr[20]; // sliding window [w0-2 .. w0+17]
#pragma unroll
      for (int m = 0; m < 20; m++) {
        int iw = w0 + m - 2;
        xr[m] = (iw >= 0 && iw <= 63) ? xp[ih * 64 + iw] : 0.f;
      }
#pragma unroll
      for (int kx = 0; kx < 5; kx++) {
        float wv = wq[ky * 5 + kx];
#pragma unroll
        for (int j = 0; j < 16; j++) o[j] = fmaf(wv, xr[j + kx], o[j]);
      }
    }
    // upsample add
    const float* ap = attb + ((size_t)b * NC + c) * NTOK;
#pragma unroll
    for (int j = 0; j < 16; j++) {
      int w = w0 + j;
      int jw0, jw1;
      float wwa, wwb;
      bil(w, jw0, jw1, wwa, wwb);
      float up = wha * (wwa * ap[jh0 * 32 + jw0] + wwb * ap[jh0 * 32 + jw1]) +
                 whb * (wwa * ap[jh1 * 32 + jw0] + wwb * ap[jh1 * 32 + jw1]);
      o[j] += up;
    }
  }
#pragma unroll
  for (int j = 0; j < 16; j++) mlds[ci2 * 65 + w0 + j] = pkf16(o0[j], o1[j]);
  __syncthreads();

  // phase 2: final 1x1, 32 outputs/thread
  int px = t & 63;
  int cg = __builtin_amdgcn_readfirstlane(t >> 6); // wave-uniform -> s_loads
  float acc[32];
#pragma unroll
  for (int i = 0; i < 32; i++) acc[i] = outb[cg * 32 + i];
  const unsigned* wpf = wph + 24576 + (size_t)cg * 32 * 64;
  for (int ci = 0; ci < 64; ci++) {
    unsigned mv = mlds[ci * 65 + px];
#pragma unroll
    for (int i = 0; i < 32; i++) acc[i] = fdot2(mv, wpf[i * 64 + ci], acc[i]);
  }
#pragma unroll
  for (int i = 0; i < 32; i++)
    out[((size_t)b * NC + cg * 32 + i) * 4096 + h0 * 64 + px] = acc[i];
}

// ---------------------------------------------------------------
extern "C" void kernel_launch(void* const* d_in, const int* in_sizes, int n_in,
                              void* d_out, int out_size, void* d_ws, size_t ws_size,
                              hipStream_t stream) {
  const float* x      = (const float*)d_in[0];
  const float* y      = (const float*)d_in[1];
  const float* rel    = (const float*)d_in[2];
  const float* q1_w   = (const float*)d_in[3];
  const float* q1_b   = (const float*)d_in[4];
  const float* q2_w   = (const float*)d_in[5];
  const float* q2_b   = (const float*)d_in[6];
  const float* kv1_w  = (const float*)d_in[7];
  const float* kv1_b  = (const float*)d_in[8];
  const float* kv2_w  = (const float*)d_in[9];
  const float* kv2_b  = (const float*)d_in[10];
  const float* lepe_w = (const float*)d_in[11];
  const float* lepe_b = (const float*)d_in[12];
  const float* out_w  = (const float*)d_in[13];
  const float* out_b  = (const float*)d_in[14];
  const float* temp   = (const float*)d_in[15];
  float* out = (float*)d_out;

  float* ws = (float*)d_ws;
  const size_t SP = (size_t)NB * NC * NTOK;   // 1,048,576
  float* attb = ws;                                        // SP f32 (4MB)
  unsigned* xph   = (unsigned*)(attb + SP);                // 512K u32 (2MB)
  unsigned* yph   = xph + 524288;                          // 512K u32 (2MB)
  unsigned* qh    = yph + 524288;                          // 512K u32 (2MB)
  unsigned* kpair = qh + 524288;                           // 512K u32 (2MB)
  unsigned short* vbf = (unsigned short*)(kpair + 524288); // SP ushorts (2MB)
  unsigned* wph   = (unsigned*)(vbf + SP);                 // 32768 u32 (128KB)

  k_prep<<<4224, 256, 0, stream>>>(x, y, q1_w, kv1_w, out_w, xph, yph, wph);
  k_qkv<<<768, 1024, 0, stream>>>(xph, yph, wph, q1_b, q2_w, q2_b,
                                  kv1_b, kv2_w, kv2_b, qh, kpair, vbf);
  k_attn<<<2048, 512, 0, stream>>>(qh, kpair, vbf, rel, temp, attb);
  k_midfinal<<<512, 256, 0, stream>>>(x, lepe_w, lepe_b, attb, wph, out_b, out);
}

// Round 19
// 166.805 us; speedup vs baseline: 1.2385x; 1.2385x over previous
//
#include <hip/hip_runtime.h>

// Problem constants
#define NB 8
#define NC 128
#define NH 64
#define NW 64
#define HEADS 4
#define HP 32
#define WP 32
#define NTOK 1024     // HP*WP
#define TOPK 32
#define HDIM 32

typedef __fp16 hh2 __attribute__((ext_vector_type(2)));

__device__ __forceinline__ hh2 h2cast(unsigned u) {
  union { unsigned u; hh2 h; } x; x.u = u; return x.h;
}
__device__ __forceinline__ unsigned pkf16(float a, float b) {
  union { hh2 h; unsigned u; } x; x.h = __builtin_amdgcn_cvt_pkrtz(a, b); return x.u;
}

#if __has_builtin(__builtin_amdgcn_fdot2)
__device__ __forceinline__ float fdot2(unsigned kw, unsigned qw, float c) {
  return __builtin_amdgcn_fdot2(h2cast(kw), h2cast(qw), c, false);
}
#else
__device__ __forceinline__ float fdot2(unsigned kw, unsigned qw, float c) {
  hh2 k = h2cast(kw), q = h2cast(qw);
  return fmaf((float)k.x, (float)q.x, fmaf((float)k.y, (float)q.y, c));
}
#endif

// monotone float->uint map (order-preserving) and inverse
__device__ __forceinline__ unsigned fmap(float f) {
  unsigned u = __float_as_uint(f);
  return u ^ ((unsigned)((int)u >> 31) | 0x80000000u);
}
__device__ __forceinline__ float funmap(unsigned k) {
  unsigned uo = k ^ ((unsigned)((int)(~k) >> 31) | 0x80000000u);
  return __uint_as_float(uo);
}

// DPP wave64 max-reduce on unsigned; result broadcast via readlane(63)
__device__ __forceinline__ unsigned wave_maxu(unsigned v) {
#define ST(ctrl)                                                                     \
  {                                                                                  \
    unsigned o = (unsigned)__builtin_amdgcn_update_dpp(0, (int)v, ctrl, 0xF, 0xF, true); \
    v = v > o ? v : o;                                                               \
  }
  ST(0xB1)   // quad_perm [1,0,3,2]
  ST(0x4E)   // quad_perm [2,3,0,1]
  ST(0x141)  // row_half_mirror
  ST(0x140)  // row_mirror
  ST(0x142)  // row_bcast:15
  ST(0x143)  // row_bcast:31
#undef ST
  return (unsigned)__builtin_amdgcn_readlane((int)v, 63);
}

// DPP wave64 float sum-reduce; result broadcast via readlane(63)
__device__ __forceinline__ float wave_sumf(float v) {
#define STA(ctrl)                                                                    \
  v += __int_as_float(__builtin_amdgcn_update_dpp(0, __float_as_int(v), ctrl, 0xF, 0xF, true));
  STA(0xB1)
  STA(0x4E)
  STA(0x141)
  STA(0x140)
  STA(0x142)
  STA(0x143)
#undef STA
  return __int_as_float(__builtin_amdgcn_readlane(__float_as_int(v), 63));
}

// DPP wave64 inclusive prefix-sum on unsigned. Safe for packed 16+16 fields.
__device__ __forceinline__ unsigned wave_iprefix(unsigned v, int lane) {
#define SH(ctrl)                                                                     \
  v += (unsigned)__builtin_amdgcn_update_dpp(0, (int)v, ctrl, 0xF, 0xF, true);
  SH(0x111)  // row_shr:1
  SH(0x112)  // row_shr:2
  SH(0x114)  // row_shr:4
  SH(0x118)  // row_shr:8
#undef SH
  unsigned r0 = (unsigned)__builtin_amdgcn_readlane((int)v, 15);
  unsigned r1 = (unsigned)__builtin_amdgcn_readlane((int)v, 31);
  unsigned r2 = (unsigned)__builtin_amdgcn_readlane((int)v, 47);
  v += (lane >= 16) ? r0 : 0u;
  v += (lane >= 32) ? r1 : 0u;
  v += (lane >= 48) ? r2 : 0u;
  return v;
}

// ---------------------------------------------------------------
// prep: avg-pool x,y -> f16 channel-pairs AND pack conv weights to f16 pairs.
__global__ void k_prep(const float* __restrict__ x, const float* __restrict__ y,
                       const float* __restrict__ q1w, const float* __restrict__ kv1w,
                       const float* __restrict__ outw,
                       unsigned* __restrict__ xph, unsigned* __restrict__ yph,
                       unsigned* __restrict__ wph) {
  int idx = blockIdx.x * 256 + threadIdx.x;
  const int total = NB * 64 * NTOK; // 524288 pairs per array
  if (idx < 2 * total) {
    bool isY = idx >= total;
    int i = isY ? idx - total : idx;
    int p = i & 1023;
    int pw = p & 31, ph = p >> 5;
    int bc2 = i >> 10;
    int c2 = bc2 & 63, b = bc2 >> 6;
    const float* s0 = (isY ? y : x) + (((size_t)b * NC + 2 * c2) * 64 + ph * 2) * 64 + pw * 2;
    const float* s1 = s0 + 4096;
    float v0 = 0.25f * (s0[0] + s0[1] + s0[64] + s0[65]);
    float v1 = 0.25f * (s1[0] + s1[1] + s1[64] + s1[65]);
    (isY ? yph : xph)[i] = pkf16(v0, v1);
  } else {
    int i = idx - 2 * total;
    if (i >= 32768) return;
    const float* src;
    int off;
    if (i < 8192) { src = q1w; off = i; }
    else if (i < 24576) { src = kv1w; off = i - 8192; }
    else { src = outw; off = i - 24576; }
    int co = off >> 6, ci2 = off & 63;
    wph[i] = pkf16(src[co * 128 + 2 * ci2], src[co * 128 + 2 * ci2 + 1]);
  }
}

// ---------------------------------------------------------------
// unified q/kv path: f16-dot2 1x1 conv (4 ch/thread) -> LDS tile -> 3x3
// (depthwise for q, grouped-2 for kv). grid = 8b x 96 units (32 q + 64 kv).
__launch_bounds__(1024, 2)
__global__ void k_qkv(const unsigned* __restrict__ xph, const unsigned* __restrict__ yph,
                      const unsigned* __restrict__ wph,
                      const float* __restrict__ q1b, const float* __restrict__ q2w,
                      const float* __restrict__ q2b,
                      const float* __restrict__ kv1b, const float* __restrict__ kv2w,
                      const float* __restrict__ kv2b,
                      unsigned* __restrict__ qh, unsigned* __restrict__ kpair,
                      unsigned short* __restrict__ vbf) {
  __shared__ float cls[4][1024];
  int px = threadIdx.x;
  int bid = blockIdx.x;
  int b = bid / 96;
  int u = bid - b * 96;
  bool isQ = u < 32;
  int q = isQ ? u : u - 32;

  const unsigned* ip = (isQ ? xph : yph) + (size_t)b * 64 * NTOK + px;
  const unsigned* wp = wph + (isQ ? 0 : 8192) + q * 4 * 64;
  const float* bb = isQ ? q1b : kv1b;
  float acc[4];
#pragma unroll
  for (int i = 0; i < 4; i++) acc[i] = bb[q * 4 + i];
  for (int ci2 = 0; ci2 < 64; ci2++) {
    unsigned mv = ip[ci2 * NTOK];
#pragma unroll
    for (int i = 0; i < 4; i++) acc[i] = fdot2(mv, wp[i * 64 + ci2], acc[i]);
  }
#pragma unroll
  for (int i = 0; i < 4; i++) cls[i][px] = acc[i];
  __syncthreads();
  int pw = px & 31, ph = px >> 5;

  if (isQ) {
    float aout[4];
#pragma unroll
    for (int i = 0; i < 4; i++) {
      int c = q * 4 + i;
      const float* wq = q2w + c * 9;
      float a = q2b[c];
#pragma unroll
      for (int ky = 0; ky < 3; ky++) {
        int ih = ph + ky - 1;
        if (ih < 0 || ih > 31) continue;
#pragma unroll
        for (int kx = 0; kx < 3; kx++) {
          int iw = pw + kx - 1;
          if (iw < 0 || iw > 31) continue;
          a = fmaf(wq[ky * 3 + kx], cls[i][ih * 32 + iw], a);
        }
      }
      aout[i] = a;
    }
    int h = q >> 3;
    int d2 = ((q * 4) & 31) >> 1;
    size_t base = (((size_t)b * HEADS + h) * NTOK + px) * 16;
    qh[base + d2] = pkf16(aout[0], aout[1]);
    qh[base + d2 + 1] = pkf16(aout[2], aout[3]);
  } else {
    float aout[4];
#pragma unroll
    for (int i = 0; i < 4; i++) {
      int o = q * 4 + i;       // kv channel 0..255
      int l0 = i & ~1;         // group's first input channel within the quad
      const float* wq = kv2w + o * 18; // [2][3][3]
      float a = kv2b[o];
#pragma unroll
      for (int ky = 0; ky < 3; ky++) {
        int ih = ph + ky - 1;
        if (ih < 0 || ih > 31) continue;
#pragma unroll
        for (int kx = 0; kx < 3; kx++) {
          int iw = pw + kx - 1;
          if (iw < 0 || iw > 31) continue;
          a = fmaf(wq[ky * 3 + kx], cls[l0][ih * 32 + iw], a);
          a = fmaf(wq[9 + ky * 3 + kx], cls[l0 + 1][ih * 32 + iw], a);
        }
      }
      aout[i] = a;
    }
    if (q < 32) {
      // K channels: quad = 4 consecutive d within head h
      int h = q >> 3;
      int d2 = ((q * 4) & 31) >> 1;
      size_t base = (((size_t)b * HEADS + h) * 16) * NTOK + px;
      kpair[base + (size_t)d2 * NTOK] = pkf16(aout[0], aout[1]);
      kpair[base + (size_t)(d2 + 1) * NTOK] = pkf16(aout[2], aout[3]);
    } else {
      // V channels
#pragma unroll
      for (int i = 0; i < 4; i++) {
        int c = q * 4 + i - 128;
        int h = c >> 5, d = c & 31;
        union { __fp16 h; unsigned short u; } cv;
        cv.h = (__fp16)aout[i];
        vbf[(((size_t)b * HEADS + h) * NTOK + px) * HDIM + d] = cv.u;
      }
    }
  }
}

// ---------------------------------------------------------------
// attention v13: round-16 structure (LDS-staged K, 2 rows/wave) + rel rows
// prefetched into registers BEFORE the staging barrier so their HBM latency
// is absorbed by the barrier wait instead of stalling the pack phase.
// grid: 2048 = 64 chunks x 4 h x 8 b; block 512 (8 waves).
__launch_bounds__(512, 2)
__global__ void k_attn(const unsigned* __restrict__ qh, const unsigned* __restrict__ kpair,
                       const unsigned short* __restrict__ vbf, const float* __restrict__ rel,
                       const float* __restrict__ temp, float* __restrict__ att) {
  __shared__ __align__(16) unsigned ksh[16384];  // f16 K pairs [d2][n], 64KB
  __shared__ __align__(16) unsigned cbuf[8 * 64]; // per-wave 32x(key,token), 2KB

  int bid = blockIdx.x;
  int chunk = bid & 63;
  int h = (bid >> 6) & 3;
  int b = bid >> 8;
  int tid = threadIdx.x;
  int lane = tid & 63;
  int wave = __builtin_amdgcn_readfirstlane(tid >> 6); // 0..7, uniform

  int qbase = chunk * 16 + wave * 2;

  // ---- issue rel prefetch FIRST (HBM latency hidden behind staging+barrier)
  const float4* relp = (const float4*)(rel + (((size_t)b * HEADS + h) * NTOK + qbase) * NTOK);
  float4 rv[2][4];
#pragma unroll
  for (int r = 0; r < 2; r++)
#pragma unroll
    for (int i = 0; i < 4; i++) rv[r][i] = relp[r * 256 + i * 64 + lane];

  // ---- q pairs (wave-uniform) ----
  unsigned qp[2][16];
#pragma unroll
  for (int r = 0; r < 2; r++) {
    const uint4* q4 = (const uint4*)(qh + (((size_t)b * HEADS + h) * NTOK + qbase + r) * 16);
#pragma unroll
    for (int i = 0; i < 4; i++) {
      uint4 t = q4[i];
      qp[r][i * 4 + 0] = t.x;
      qp[r][i * 4 + 1] = t.y;
      qp[r][i * 4 + 2] = t.z;
      qp[r][i * 4 + 3] = t.w;
    }
  }

  // ---- stage K pairs: 16384 u32 = 8192 uint2, 512 threads x 16 ----
  const uint2* kg = (const uint2*)(kpair + ((size_t)b * HEADS + h) * 16 * NTOK);
  uint2* kl = (uint2*)ksh;
#pragma unroll
  for (int i = 0; i < 16; i++) kl[tid + i * 512] = kg[tid + i * 512];
  __syncthreads();

  const float tmpr = temp[h];
  const unsigned short* vb = vbf + ((size_t)(b * HEADS + h)) * NTOK * HDIM;
  int vlane = lane & 31;
  unsigned* row_lds = cbuf + wave * 64; // 32 entries x 8B, private per wave

  // logits via f16 dot2: acc[r][e] += K[d2](tok) . q[r][d2]
  float acc[2][16];
#pragma unroll
  for (int r = 0; r < 2; r++)
#pragma unroll
    for (int e = 0; e < 16; e++) acc[r][e] = 0.f;

#pragma unroll 4
  for (int d2 = 0; d2 < 16; d2++) {
#pragma unroll
    for (int i = 0; i < 4; i++) {
      uint4 kw = *(const uint4*)&ksh[d2 * 1024 + i * 256 + lane * 4]; // tokens i*256+lane*4+m
      acc[0][i * 4 + 0] = fdot2(kw.x, qp[0][d2], acc[0][i * 4 + 0]);
      acc[0][i * 4 + 1] = fdot2(kw.y, qp[0][d2], acc[0][i * 4 + 1]);
      acc[0][i * 4 + 2] = fdot2(kw.z, qp[0][d2], acc[0][i * 4 + 2]);
      acc[0][i * 4 + 3] = fdot2(kw.w, qp[0][d2], acc[0][i * 4 + 3]);
      acc[1][i * 4 + 0] = fdot2(kw.x, qp[1][d2], acc[1][i * 4 + 0]);
      acc[1][i * 4 + 1] = fdot2(kw.y, qp[1][d2], acc[1][i * 4 + 1]);
      acc[1][i * 4 + 2] = fdot2(kw.z, qp[1][d2], acc[1][i * 4 + 2]);
      acc[1][i * 4 + 3] = fdot2(kw.w, qp[1][d2], acc[1][i * 4 + 3]);
    }
  }

  // pack keys, fusing rel (already in registers)
  unsigned kk[2][16];
#pragma unroll
  for (int r = 0; r < 2; r++) {
#pragma unroll
    for (int i = 0; i < 4; i++) {
      kk[r][i * 4 + 0] = fmap(fmaf(tmpr, acc[r][i * 4 + 0], rv[r][i].x));
      kk[r][i * 4 + 1] = fmap(fmaf(tmpr, acc[r][i * 4 + 1], rv[r][i].y));
      kk[r][i * 4 + 2] = fmap(fmaf(tmpr, acc[r][i * 4 + 2], rv[r][i].z));
      kk[r][i * 4 + 3] = fmap(fmaf(tmpr, acc[r][i * 4 + 3], rv[r][i].w));
    }
  }

  // wave max per row (bsearch upper bound + softmax max)
  unsigned M[2];
#pragma unroll
  for (int r = 0; r < 2; r++) {
    unsigned mx = kk[r][0];
#pragma unroll
    for (int e = 1; e < 16; e++) mx = mx > kk[r][e] ? mx : kk[r][e];
    M[r] = wave_maxu(mx);
  }

  // early-exit binary search; cap 32 -> exact-tie fallback
  unsigned lo0 = 0u, hi0 = M[0], lo1 = 0u, hi1 = M[1];
  unsigned T0x = 0u, T1x = 0u;
  bool d0 = false, d1 = false;
#pragma unroll 1
  for (int it = 0; it < 32; it++) {
    if (d0 && d1) break;
    if (!d0) {
      unsigned mid = lo0 + ((hi0 - lo0) >> 1);
      int c = 0;
#pragma unroll
      for (int e = 0; e < 16; e++) c += (int)__popcll(__ballot(kk[0][e] > mid));
      if (c >= TOPK) lo0 = mid; else hi0 = mid;
      if (c == TOPK) { T0x = mid; d0 = true; }
    }
    if (!d1) {
      unsigned mid = lo1 + ((hi1 - lo1) >> 1);
      int c = 0;
#pragma unroll
      for (int e = 0; e < 16; e++) c += (int)__popcll(__ballot(kk[1][e] > mid));
      if (c >= TOPK) lo1 = mid; else hi1 = mid;
      if (c == TOPK) { T1x = mid; d1 = true; }
    }
  }
  unsigned T[2];
  T[0] = d0 ? T0x : hi0;
  T[1] = d1 ? T1x : hi1;

  // per-row: tie handling, compaction, softmax + V gather
#pragma unroll
  for (int r = 0; r < 2; r++) {
    unsigned gtc = 0, tq = 0;
#pragma unroll
    for (int e = 0; e < 16; e++) {
      gtc += (kk[r][e] > T[r]) ? 1u : 0u;
      tq += (kk[r][e] == T[r]) ? 1u : 0u;
    }
    unsigned packed = gtc | (tq << 16);
    unsigned incl = wave_iprefix(packed, lane);
    unsigned tot = (unsigned)__builtin_amdgcn_readlane((int)incl, 63);
    unsigned n_gt = tot & 0xFFFFu;
    unsigned tie_pfx = (incl >> 16) - tq;
    unsigned extras = (unsigned)TOPK - n_gt; // 0 on early-exit rows
    int el = (int)extras - (int)tie_pfx;
    el = el < 0 ? 0 : el;
    el = el > (int)tq ? (int)tq : el;
    unsigned sc = gtc + (unsigned)el;
    unsigned wbase = wave_iprefix(sc, lane) - sc;

    unsigned wp = wbase, tr = tie_pfx;
#pragma unroll
    for (int e = 0; e < 16; e++) {
      bool gt = kk[r][e] > T[r];
      bool eq = (kk[r][e] == T[r]);
      bool take = gt || (eq && (tr < extras));
      tr += eq ? 1u : 0u;
      if (take) {
        ((uint2*)row_lds)[wp] = make_uint2(kk[r][e], (unsigned)((e >> 2) * 256 + lane * 4 + (e & 3)));
        wp++;
      }
    }

    // parallel softmax over the 32 entries (lanes 0..31) + pipelined V gather
    uint2 ent = ((const uint2*)row_lds)[vlane];
    float fv = funmap(ent.x);
    float mv = funmap(M[r]);
    float e_ = __expf(fv - mv);
    e_ = (lane < TOPK) ? e_ : 0.f;
    float se = wave_sumf(e_);

    float oacc = 0.f;
#pragma unroll
    for (int t = 0; t < TOPK; t++) {
      float es = __int_as_float(__builtin_amdgcn_readlane(__float_as_int(e_), t));
      int tok = __builtin_amdgcn_readlane((int)ent.y, t);
      union { unsigned short u; __fp16 h; } cv;
      cv.u = vb[(size_t)tok * HDIM + vlane];
      oacc = fmaf(es, (float)cv.h, oacc);
    }

    if (lane < HDIM) {
      att[((size_t)b * NC + h * HDIM + lane) * NTOK + (qbase + r)] = oacc / se;
    }
  }
}

// ---------------------------------------------------------------
// bilinear 2x upsample weights (jax scale_and_translate semantics)
__device__ __forceinline__ void bil(int i, int& j0, int& j1, float& wa, float& wb) {
  if (i & 1) {
    j0 = i >> 1; j1 = j0 + 1; wa = 0.75f; wb = 0.25f;
    if (j1 > 31) { j1 = 31; wa = 1.f; wb = 0.f; }
  } else {
    j0 = (i >> 1) - 1; j1 = j0 + 1; wa = 0.25f; wb = 0.75f;
    if (j0 < 0) { j0 = 0; wa = 0.f; wb = 1.f; }
  }
}

// ---------------------------------------------------------------
// fused mid+final: phase 1 computes lepe+upsample for all 128 channels of
// one 64-px output row into LDS (f16 pairs, padded [64][65]); phase 2 runs
// the final 1x1 conv (f16-dot2, scalar-hoisted weights) from LDS.
// grid: 512 = 8b x 64 rows; block 256.
__launch_bounds__(256, 4)
__global__ void k_midfinal(const float* __restrict__ x, const float* __restrict__ lepe_w,
                           const float* __restrict__ lepe_b, const float* __restrict__ attb,
                           const unsigned* __restrict__ wph, const float* __restrict__ outb,
                           float* __restrict__ out) {
  __shared__ unsigned mlds[64 * 65]; // [ci2][px], +1 pad -> 2-way banks (free)
  int bid = blockIdx.x;
  int h0 = bid & 63;
  int b = bid >> 6;
  int t = threadIdx.x;
  int ci2 = t >> 2;
  int w0 = (t & 3) * 16;

  int jh0, jh1;
  float wha, whb;
  bil(h0, jh0, jh1, wha, whb);

  float o0[16], o1[16];
#pragma unroll
  for (int cc = 0; cc < 2; cc++) {
    int c = 2 * ci2 + cc;
    const float* xp = x + ((size_t)b * NC + c) * 4096;
    const float* wq = lepe_w + c * 25;
    float* o = cc ? o1 : o0;
    float bv = lepe_b[c];
#pragma unroll
    for (int j = 0; j < 16; j++) o[j] = bv;
#pragma unroll
    for (int ky = 0; ky < 5; ky++) {
      int ih = h0 + ky - 2;
      if (ih < 0 || ih > 63) continue;
      float xr[20]; // sliding window [w0-2 .. w0+17]
#pragma unroll
      for (int m = 0; m < 20; m++) {
        int iw = w0 + m - 2;
        xr[m] = (iw >= 0 && iw <= 63) ? xp[ih * 64 + iw] : 0.f;
      }
#pragma unroll
      for (int kx = 0; kx < 5; kx++) {
        float wv = wq[ky * 5 + kx];
#pragma unroll
        for (int j = 0; j < 16; j++) o[j] = fmaf(wv, xr[j + kx], o[j]);
      }
    }
    // upsample add
    const float* ap = attb + ((size_t)b * NC + c) * NTOK;
#pragma unroll
    for (int j = 0; j < 16; j++) {
      int w = w0 + j;
      int jw0, jw1;
      float wwa, wwb;
      bil(w, jw0, jw1, wwa, wwb);
      float up = wha * (wwa * ap[jh0 * 32 + jw0] + wwb * ap[jh0 * 32 + jw1]) +
                 whb * (wwa * ap[jh1 * 32 + jw0] + wwb * ap[jh1 * 32 + jw1]);
      o[j] += up;
    }
  }
#pragma unroll
  for (int j = 0; j < 16; j++) mlds[ci2 * 65 + w0 + j] = pkf16(o0[j], o1[j]);
  __syncthreads();

  // phase 2: final 1x1, 32 outputs/thread
  int px = t & 63;
  int cg = __builtin_amdgcn_readfirstlane(t >> 6); // wave-uniform -> s_loads
  float acc[32];
#pragma unroll
  for (int i = 0; i < 32; i++) acc[i] = outb[cg * 32 + i];
  const unsigned* wpf = wph + 24576 + (size_t)cg * 32 * 64;
  for (int ci = 0; ci < 64; ci++) {
    unsigned mv = mlds[ci * 65 + px];
#pragma unroll
    for (int i = 0; i < 32; i++) acc[i] = fdot2(mv, wpf[i * 64 + ci], acc[i]);
  }
#pragma unroll
  for (int i = 0; i < 32; i++)
    out[((size_t)b * NC + cg * 32 + i) * 4096 + h0 * 64 + px] = acc[i];
}

// ---------------------------------------------------------------
extern "C" void kernel_launch(void* const* d_in, const int* in_sizes, int n_in,
                              void* d_out, int out_size, void* d_ws, size_t ws_size,
                              hipStream_t stream) {
  const float* x      = (const float*)d_in[0];
  const float* y      = (const float*)d_in[1];
  const float* rel    = (const float*)d_in[2];
  const float* q1_w   = (const float*)d_in[3];
  const float* q1_b   = (const float*)d_in[4];
  const float* q2_w   = (const float*)d_in[5];
  const float* q2_b   = (const float*)d_in[6];
  const float* kv1_w  = (const float*)d_in[7];
  const float* kv1_b  = (const float*)d_in[8];
  const float* kv2_w  = (const float*)d_in[9];
  const float* kv2_b  = (const float*)d_in[10];
  const float* lepe_w = (const float*)d_in[11];
  const float* lepe_b = (const float*)d_in[12];
  const float* out_w  = (const float*)d_in[13];
  const float* out_b  = (const float*)d_in[14];
  const float* temp   = (const float*)d_in[15];
  float* out = (float*)d_out;

  float* ws = (float*)d_ws;
  const size_t SP = (size_t)NB * NC * NTOK;   // 1,048,576
  float* attb = ws;                                        // SP f32 (4MB)
  unsigned* xph   = (unsigned*)(attb + SP);                // 512K u32 (2MB)
  unsigned* yph   = xph + 524288;                          // 512K u32 (2MB)
  unsigned* qh    = yph + 524288;                          // 512K u32 (2MB)
  unsigned* kpair = qh + 524288;                           // 512K u32 (2MB)
  unsigned short* vbf = (unsigned short*)(kpair + 524288); // SP ushorts (2MB)
  unsigned* wph   = (unsigned*)(vbf + SP);                 // 32768 u32 (128KB)

  k_prep<<<4224, 256, 0, stream>>>(x, y, q1_w, kv1_w, out_w, xph, yph, wph);
  k_qkv<<<768, 1024, 0, stream>>>(xph, yph, wph, q1_b, q2_w, q2_b,
                                  kv1_b, kv2_w, kv2_b, qh, kpair, vbf);
  k_attn<<<2048, 512, 0, stream>>>(qh, kpair, vbf, rel, temp, attb);
  k_midfinal<<<512, 256, 0, stream>>>(x, lepe_w, lepe_b, attb, wph, out_b, out);
}

// Round 20
// 156.189 us; speedup vs baseline: 1.3227x; 1.0680x over previous
//
#include <hip/hip_runtime.h>

// Problem constants
#define NB 8
#define NC 128
#define NH 64
#define NW 64
#define HEADS 4
#define HP 32
#define WP 32
#define NTOK 1024     // HP*WP
#define TOPK 32
#define HDIM 32

typedef __fp16 hh2 __attribute__((ext_vector_type(2)));
typedef __fp16 half8 __attribute__((ext_vector_type(8)));
typedef float v4f __attribute__((ext_vector_type(4)));

__device__ __forceinline__ hh2 h2cast(unsigned u) {
  union { unsigned u; hh2 h; } x; x.u = u; return x.h;
}
__device__ __forceinline__ unsigned pkf16(float a, float b) {
  union { hh2 h; unsigned u; } x; x.h = __builtin_amdgcn_cvt_pkrtz(a, b); return x.u;
}
__device__ __forceinline__ half8 h8cast(uint4 u) {
  union { uint4 u; half8 h; } x; x.u = u; return x.h;
}

#if __has_builtin(__builtin_amdgcn_fdot2)
__device__ __forceinline__ float fdot2(unsigned kw, unsigned qw, float c) {
  return __builtin_amdgcn_fdot2(h2cast(kw), h2cast(qw), c, false);
}
#else
__device__ __forceinline__ float fdot2(unsigned kw, unsigned qw, float c) {
  hh2 k = h2cast(kw), q = h2cast(qw);
  return fmaf((float)k.x, (float)q.x, fmaf((float)k.y, (float)q.y, c));
}
#endif

// monotone float->uint map (order-preserving) and inverse
__device__ __forceinline__ unsigned fmap(float f) {
  unsigned u = __float_as_uint(f);
  return u ^ ((unsigned)((int)u >> 31) | 0x80000000u);
}
__device__ __forceinline__ float funmap(unsigned k) {
  unsigned uo = k ^ ((unsigned)((int)(~k) >> 31) | 0x80000000u);
  return __uint_as_float(uo);
}

// DPP wave64 max-reduce on unsigned; result broadcast via readlane(63)
__device__ __forceinline__ unsigned wave_maxu(unsigned v) {
#define ST(ctrl)                                                                     \
  {                                                                                  \
    unsigned o = (unsigned)__builtin_amdgcn_update_dpp(0, (int)v, ctrl, 0xF, 0xF, true); \
    v = v > o ? v : o;                                                               \
  }
  ST(0xB1)   // quad_perm [1,0,3,2]
  ST(0x4E)   // quad_perm [2,3,0,1]
  ST(0x141)  // row_half_mirror
  ST(0x140)  // row_mirror
  ST(0x142)  // row_bcast:15
  ST(0x143)  // row_bcast:31
#undef ST
  return (unsigned)__builtin_amdgcn_readlane((int)v, 63);
}

// DPP wave64 float sum-reduce; result broadcast via readlane(63)
__device__ __forceinline__ float wave_sumf(float v) {
#define STA(ctrl)                                                                    \
  v += __int_as_float(__builtin_amdgcn_update_dpp(0, __float_as_int(v), ctrl, 0xF, 0xF, true));
  STA(0xB1)
  STA(0x4E)
  STA(0x141)
  STA(0x140)
  STA(0x142)
  STA(0x143)
#undef STA
  return __int_as_float(__builtin_amdgcn_readlane(__float_as_int(v), 63));
}

// DPP wave64 inclusive prefix-sum on unsigned. Safe for packed 16+16 fields.
__device__ __forceinline__ unsigned wave_iprefix(unsigned v, int lane) {
#define SH(ctrl)                                                                     \
  v += (unsigned)__builtin_amdgcn_update_dpp(0, (int)v, ctrl, 0xF, 0xF, true);
  SH(0x111)  // row_shr:1
  SH(0x112)  // row_shr:2
  SH(0x114)  // row_shr:4
  SH(0x118)  // row_shr:8
#undef SH
  unsigned r0 = (unsigned)__builtin_amdgcn_readlane((int)v, 15);
  unsigned r1 = (unsigned)__builtin_amdgcn_readlane((int)v, 31);
  unsigned r2 = (unsigned)__builtin_amdgcn_readlane((int)v, 47);
  v += (lane >= 16) ? r0 : 0u;
  v += (lane >= 32) ? r1 : 0u;
  v += (lane >= 48) ? r2 : 0u;
  return v;
}

// ---------------------------------------------------------------
// prep: avg-pool x,y -> f16 channel-pairs AND pack conv weights to f16 pairs.
__global__ void k_prep(const float* __restrict__ x, const float* __restrict__ y,
                       const float* __restrict__ q1w, const float* __restrict__ kv1w,
                       const float* __restrict__ outw,
                       unsigned* __restrict__ xph, unsigned* __restrict__ yph,
                       unsigned* __restrict__ wph) {
  int idx = blockIdx.x * 256 + threadIdx.x;
  const int total = NB * 64 * NTOK; // 524288 pairs per array
  if (idx < 2 * total) {
    bool isY = idx >= total;
    int i = isY ? idx - total : idx;
    int p = i & 1023;
    int pw = p & 31, ph = p >> 5;
    int bc2 = i >> 10;
    int c2 = bc2 & 63, b = bc2 >> 6;
    const float* s0 = (isY ? y : x) + (((size_t)b * NC + 2 * c2) * 64 + ph * 2) * 64 + pw * 2;
    const float* s1 = s0 + 4096;
    float v0 = 0.25f * (s0[0] + s0[1] + s0[64] + s0[65]);
    float v1 = 0.25f * (s1[0] + s1[1] + s1[64] + s1[65]);
    (isY ? yph : xph)[i] = pkf16(v0, v1);
  } else {
    int i = idx - 2 * total;
    if (i >= 32768) return;
    const float* src;
    int off;
    if (i < 8192) { src = q1w; off = i; }
    else if (i < 24576) { src = kv1w; off = i - 8192; }
    else { src = outw; off = i - 24576; }
    int co = off >> 6, ci2 = off & 63;
    wph[i] = pkf16(src[co * 128 + 2 * ci2], src[co * 128 + 2 * ci2 + 1]);
  }
}

// ---------------------------------------------------------------
// unified q/kv path: f16-dot2 1x1 conv (4 ch/thread) -> LDS tile -> 3x3
// (depthwise for q, grouped-2 for kv). K now written TOKEN-MAJOR (like q):
// ktd[((b*4+h)*1024+tok)*16 + d2]. grid = 8b x 96 units (32 q + 64 kv).
__launch_bounds__(1024, 2)
__global__ void k_qkv(const unsigned* __restrict__ xph, const unsigned* __restrict__ yph,
                      const unsigned* __restrict__ wph,
                      const float* __restrict__ q1b, const float* __restrict__ q2w,
                      const float* __restrict__ q2b,
                      const float* __restrict__ kv1b, const float* __restrict__ kv2w,
                      const float* __restrict__ kv2b,
                      unsigned* __restrict__ qh, unsigned* __restrict__ ktd,
                      unsigned short* __restrict__ vbf) {
  __shared__ float cls[4][1024];
  int px = threadIdx.x;
  int bid = blockIdx.x;
  int b = bid / 96;
  int u = bid - b * 96;
  bool isQ = u < 32;
  int q = isQ ? u : u - 32;

  const unsigned* ip = (isQ ? xph : yph) + (size_t)b * 64 * NTOK + px;
  const unsigned* wp = wph + (isQ ? 0 : 8192) + q * 4 * 64;
  const float* bb = isQ ? q1b : kv1b;
  float acc[4];
#pragma unroll
  for (int i = 0; i < 4; i++) acc[i] = bb[q * 4 + i];
  for (int ci2 = 0; ci2 < 64; ci2++) {
    unsigned mv = ip[ci2 * NTOK];
#pragma unroll
    for (int i = 0; i < 4; i++) acc[i] = fdot2(mv, wp[i * 64 + ci2], acc[i]);
  }
#pragma unroll
  for (int i = 0; i < 4; i++) cls[i][px] = acc[i];
  __syncthreads();
  int pw = px & 31, ph = px >> 5;

  if (isQ) {
    float aout[4];
#pragma unroll
    for (int i = 0; i < 4; i++) {
      int c = q * 4 + i;
      const float* wq = q2w + c * 9;
      float a = q2b[c];
#pragma unroll
      for (int ky = 0; ky < 3; ky++) {
        int ih = ph + ky - 1;
        if (ih < 0 || ih > 31) continue;
#pragma unroll
        for (int kx = 0; kx < 3; kx++) {
          int iw = pw + kx - 1;
          if (iw < 0 || iw > 31) continue;
          a = fmaf(wq[ky * 3 + kx], cls[i][ih * 32 + iw], a);
        }
      }
      aout[i] = a;
    }
    int h = q >> 3;
    int d2 = ((q * 4) & 31) >> 1;
    size_t base = (((size_t)b * HEADS + h) * NTOK + px) * 16;
    qh[base + d2] = pkf16(aout[0], aout[1]);
    qh[base + d2 + 1] = pkf16(aout[2], aout[3]);
  } else {
    float aout[4];
#pragma unroll
    for (int i = 0; i < 4; i++) {
      int o = q * 4 + i;       // kv channel 0..255
      int l0 = i & ~1;         // group's first input channel within the quad
      const float* wq = kv2w + o * 18; // [2][3][3]
      float a = kv2b[o];
#pragma unroll
      for (int ky = 0; ky < 3; ky++) {
        int ih = ph + ky - 1;
        if (ih < 0 || ih > 31) continue;
#pragma unroll
        for (int kx = 0; kx < 3; kx++) {
          int iw = pw + kx - 1;
          if (iw < 0 || iw > 31) continue;
          a = fmaf(wq[ky * 3 + kx], cls[l0][ih * 32 + iw], a);
          a = fmaf(wq[9 + ky * 3 + kx], cls[l0 + 1][ih * 32 + iw], a);
        }
      }
      aout[i] = a;
    }
    if (q < 32) {
      // K channels, token-major f16 pairs
      int h = q >> 3;
      int d2 = ((q * 4) & 31) >> 1;
      size_t base = (((size_t)b * HEADS + h) * NTOK + px) * 16;
      ktd[base + d2] = pkf16(aout[0], aout[1]);
      ktd[base + d2 + 1] = pkf16(aout[2], aout[3]);
    } else {
      // V channels
#pragma unroll
      for (int i = 0; i < 4; i++) {
        int c = q * 4 + i - 128;
        int h = c >> 5, d = c & 31;
        union { __fp16 h; unsigned short u; } cv;
        cv.h = (__fp16)aout[i];
        vbf[(((size_t)b * HEADS + h) * NTOK + px) * HDIM + d] = cv.u;
      }
    }
  }
}

// ---------------------------------------------------------------
// attention v14: MFMA QK^T. Block = (b, h, 16-row tile), 8 waves; wave w
// computes S[16 rows][128 tokens] via 8x mfma_f32_16x16x32_f16, fuses
// rel+temp, packs monotone keys to LDS keys[16][1025]. Barrier; each wave
// then runs bsearch top-32 select + softmax + V gather on 2 rows.
// grid: 2048 = 64 tiles x 4 h x 8 b; block 512.
__launch_bounds__(512, 2)
__global__ void k_attn(const unsigned* __restrict__ qh, const unsigned* __restrict__ ktd,
                       const unsigned short* __restrict__ vbf, const float* __restrict__ rel,
                       const float* __restrict__ temp, float* __restrict__ att) {
  __shared__ unsigned keys[16 * 1025];            // packed keys, 64.1KB (pad->bank spread)
  __shared__ __align__(16) unsigned cbuf[8 * 64]; // per-wave 32x(key,token), 2KB

  int bid = blockIdx.x;
  int tile = bid & 63;
  int h = (bid >> 6) & 3;
  int b = bid >> 8;
  int tid = threadIdx.x;
  int lane = tid & 63;
  int wave = __builtin_amdgcn_readfirstlane(tid >> 6); // 0..7, uniform

  int bh = b * HEADS + h;
  int qbase = tile * 16;
  const float tmpr = temp[h];

  // ---- MFMA phase: this wave owns tokens [wave*128, wave*128+128) ----
  {
    // A fragment: Q rows qbase..qbase+15, lane holds row (lane&15),
    // k-elems (lane>>4)*8..+7  (= 4 u32 of the row's 16-u32 d-pair vector)
    const unsigned* qp = qh + ((size_t)bh * NTOK + qbase) * 16;
    uint4 aU = *(const uint4*)&qp[(lane & 15) * 16 + (lane >> 4) * 4];
    half8 aF = h8cast(aU);

    const unsigned* kt = ktd + (size_t)bh * NTOK * 16;
    const float* relp = rel + ((size_t)bh * NTOK + qbase) * NTOK + wave * 128;

#pragma unroll
    for (int f = 0; f < 8; f++) {
      int tokl = f * 16 + (lane & 15); // token offset within this wave's 128
      // B fragment: lane holds col (lane&15) = token, k-elems (lane>>4)*8..+7
      uint4 bU = *(const uint4*)&kt[((size_t)(wave * 128 + tokl)) * 16 + (lane >> 4) * 4];
      half8 bF = h8cast(bU);
      v4f c = {0.f, 0.f, 0.f, 0.f};
      c = __builtin_amdgcn_mfma_f32_16x16x32_f16(aF, bF, c, 0, 0, 0);
      // C/D: col = lane&15 (token), row = (lane>>4)*4 + j
#pragma unroll
      for (int j = 0; j < 4; j++) {
        int row = (lane >> 4) * 4 + j;
        float rv = relp[row * NTOK + tokl];
        keys[row * 1025 + wave * 128 + tokl] = fmap(fmaf(tmpr, c[j], rv));
      }
    }
  }
  __syncthreads();

  const unsigned short* vb = vbf + (size_t)bh * NTOK * HDIM;
  int vlane = lane & 31;
  unsigned* row_lds = cbuf + wave * 64; // 32 entries x 8B, private per wave

  // ---- select phase: this wave owns rows 2*wave, 2*wave+1 ----
  unsigned kk[2][16];
#pragma unroll
  for (int r = 0; r < 2; r++) {
    const unsigned* kr = &keys[(2 * wave + r) * 1025];
#pragma unroll
    for (int e = 0; e < 16; e++) kk[r][e] = kr[e * 64 + lane];
  }

  // wave max per row (bsearch upper bound + softmax max)
  unsigned M[2];
#pragma unroll
  for (int r = 0; r < 2; r++) {
    unsigned mx = kk[r][0];
#pragma unroll
    for (int e = 1; e < 16; e++) mx = mx > kk[r][e] ? mx : kk[r][e];
    M[r] = wave_maxu(mx);
  }

  // early-exit binary search; cap 32 -> exact-tie fallback
  unsigned lo0 = 0u, hi0 = M[0], lo1 = 0u, hi1 = M[1];
  unsigned T0x = 0u, T1x = 0u;
  bool d0 = false, d1 = false;
#pragma unroll 1
  for (int it = 0; it < 32; it++) {
    if (d0 && d1) break;
    if (!d0) {
      unsigned mid = lo0 + ((hi0 - lo0) >> 1);
      int c = 0;
#pragma unroll
      for (int e = 0; e < 16; e++) c += (int)__popcll(__ballot(kk[0][e] > mid));
      if (c >= TOPK) lo0 = mid; else hi0 = mid;
      if (c == TOPK) { T0x = mid; d0 = true; }
    }
    if (!d1) {
      unsigned mid = lo1 + ((hi1 - lo1) >> 1);
      int c = 0;
#pragma unroll
      for (int e = 0; e < 16; e++) c += (int)__popcll(__ballot(kk[1][e] > mid));
      if (c >= TOPK) lo1 = mid; else hi1 = mid;
      if (c == TOPK) { T1x = mid; d1 = true; }
    }
  }
  unsigned T[2];
  T[0] = d0 ? T0x : hi0;
  T[1] = d1 ? T1x : hi1;

  // per-row: tie handling, compaction, softmax + V gather
#pragma unroll
  for (int r = 0; r < 2; r++) {
    unsigned gtc = 0, tq = 0;
#pragma unroll
    for (int e = 0; e < 16; e++) {
      gtc += (kk[r][e] > T[r]) ? 1u : 0u;
      tq += (kk[r][e] == T[r]) ? 1u : 0u;
    }
    unsigned packed = gtc | (tq << 16);
    unsigned incl = wave_iprefix(packed, lane);
    unsigned tot = (unsigned)__builtin_amdgcn_readlane((int)incl, 63);
    unsigned n_gt = tot & 0xFFFFu;
    unsigned tie_pfx = (incl >> 16) - tq;
    unsigned extras = (unsigned)TOPK - n_gt; // 0 on early-exit rows
    int el = (int)extras - (int)tie_pfx;
    el = el < 0 ? 0 : el;
    el = el > (int)tq ? (int)tq : el;
    unsigned sc = gtc + (unsigned)el;
    unsigned wbase = wave_iprefix(sc, lane) - sc;

    unsigned wp = wbase, tr = tie_pfx;
#pragma unroll
    for (int e = 0; e < 16; e++) {
      bool gt = kk[r][e] > T[r];
      bool eq = (kk[r][e] == T[r]);
      bool take = gt || (eq && (tr < extras));
      tr += eq ? 1u : 0u;
      if (take) {
        ((uint2*)row_lds)[wp] = make_uint2(kk[r][e], (unsigned)(e * 64 + lane));
        wp++;
      }
    }

    // parallel softmax over the 32 entries (lanes 0..31) + pipelined V gather
    uint2 ent = ((const uint2*)row_lds)[vlane];
    float fv = funmap(ent.x);
    float mv = funmap(M[r]);
    float e_ = __expf(fv - mv);
    e_ = (lane < TOPK) ? e_ : 0.f;
    float se = wave_sumf(e_);

    float oacc = 0.f;
#pragma unroll
    for (int t = 0; t < TOPK; t++) {
      float es = __int_as_float(__builtin_amdgcn_readlane(__float_as_int(e_), t));
      int tok = __builtin_amdgcn_readlane((int)ent.y, t);
      union { unsigned short u; __fp16 h; } cv;
      cv.u = vb[(size_t)tok * HDIM + vlane];
      oacc = fmaf(es, (float)cv.h, oacc);
    }

    if (lane < HDIM) {
      att[((size_t)b * NC + h * HDIM + lane) * NTOK + (qbase + 2 * wave + r)] = oacc / se;
    }
  }
}

// ---------------------------------------------------------------
// bilinear 2x upsample weights (jax scale_and_translate semantics)
__device__ __forceinline__ void bil(int i, int& j0, int& j1, float& wa, float& wb) {
  if (i & 1) {
    j0 = i >> 1; j1 = j0 + 1; wa = 0.75f; wb = 0.25f;
    if (j1 > 31) { j1 = 31; wa = 1.f; wb = 0.f; }
  } else {
    j0 = (i >> 1) - 1; j1 = j0 + 1; wa = 0.25f; wb = 0.75f;
    if (j0 < 0) { j0 = 0; wa = 0.f; wb = 1.f; }
  }
}

// ---------------------------------------------------------------
// fused mid+final: phase 1 computes lepe+upsample for all 128 channels of
// one 64-px output row into LDS (f16 pairs, padded [64][65]); phase 2 runs
// the final 1x1 conv (f16-dot2, scalar-hoisted weights) from LDS.
// grid: 512 = 8b x 64 rows; block 256.
__launch_bounds__(256, 4)
__global__ void k_midfinal(const float* __restrict__ x, const float* __restrict__ lepe_w,
                           const float* __restrict__ lepe_b, const float* __restrict__ attb,
                           const unsigned* __restrict__ wph, const float* __restrict__ outb,
                           float* __restrict__ out) {
  __shared__ unsigned mlds[64 * 65]; // [ci2][px], +1 pad -> 2-way banks (free)
  int bid = blockIdx.x;
  int h0 = bid & 63;
  int b = bid >> 6;
  int t = threadIdx.x;
  int ci2 = t >> 2;
  int w0 = (t & 3) * 16;

  int jh0, jh1;
  float wha, whb;
  bil(h0, jh0, jh1, wha, whb);

  float o0[16], o1[16];
#pragma unroll
  for (int cc = 0; cc < 2; cc++) {
    int c = 2 * ci2 + cc;
    const float* xp = x + ((size_t)b * NC + c) * 4096;
    const float* wq = lepe_w + c * 25;
    float* o = cc ? o1 : o0;
    float bv = lepe_b[c];
#pragma unroll
    for (int j = 0; j < 16; j++) o[j] = bv;
#pragma unroll
    for (int ky = 0; ky < 5; ky++) {
      int ih = h0 + ky - 2;
      if (ih < 0 || ih > 63) continue;
      float xr[20]; // sliding window [w0-2 .. w0+17]
#pragma unroll
      for (int m = 0; m < 20; m++) {
        int iw = w0 + m - 2;
        xr[m] = (iw >= 0 && iw <= 63) ? xp[ih * 64 + iw] : 0.f;
      }
#pragma unroll
      for (int kx = 0; kx < 5; kx++) {
        float wv = wq[ky * 5 + kx];
#pragma unroll
        for (int j = 0; j < 16; j++) o[j] = fmaf(wv, xr[j + kx], o[j]);
      }
    }
    // upsample add
    const float* ap = attb + ((size_t)b * NC + c) * NTOK;
#pragma unroll
    for (int j = 0; j < 16; j++) {
      int w = w0 + j;
      int jw0, jw1;
      float wwa, wwb;
      bil(w, jw0, jw1, wwa, wwb);
      float up = wha * (wwa * ap[jh0 * 32 + jw0] + wwb * ap[jh0 * 32 + jw1]) +
                 whb * (wwa * ap[jh1 * 32 + jw0] + wwb * ap[jh1 * 32 + jw1]);
      o[j] += up;
    }
  }
#pragma unroll
  for (int j = 0; j < 16; j++) mlds[ci2 * 65 + w0 + j] = pkf16(o0[j], o1[j]);
  __syncthreads();

  // phase 2: final 1x1, 32 outputs/thread
  int px = t & 63;
  int cg = __builtin_amdgcn_readfirstlane(t >> 6); // wave-uniform -> s_loads
  float acc[32];
#pragma unroll
  for (int i = 0; i < 32; i++) acc[i] = outb[cg * 32 + i];
  const unsigned* wpf = wph + 24576 + (size_t)cg * 32 * 64;
  for (int ci = 0; ci < 64; ci++) {
    unsigned mv = mlds[ci * 65 + px];
#pragma unroll
    for (int i = 0; i < 32; i++) acc[i] = fdot2(mv, wpf[i * 64 + ci], acc[i]);
  }
#pragma unroll
  for (int i = 0; i < 32; i++)
    out[((size_t)b * NC + cg * 32 + i) * 4096 + h0 * 64 + px] = acc[i];
}

// ---------------------------------------------------------------
extern "C" void kernel_launch(void* const* d_in, const int* in_sizes, int n_in,
                              void* d_out, int out_size, void* d_ws, size_t ws_size,
                              hipStream_t stream) {
  const float* x      = (const float*)d_in[0];
  const float* y      = (const float*)d_in[1];
  const float* rel    = (const float*)d_in[2];
  const float* q1_w   = (const float*)d_in[3];
  const float* q1_b   = (const float*)d_in[4];
  const float* q2_w   = (const float*)d_in[5];
  const float* q2_b   = (const float*)d_in[6];
  const float* kv1_w  = (const float*)d_in[7];
  const float* kv1_b  = (const float*)d_in[8];
  const float* kv2_w  = (const float*)d_in[9];
  const float* kv2_b  = (const float*)d_in[10];
  const float* lepe_w = (const float*)d_in[11];
  const float* lepe_b = (const float*)d_in[12];
  const float* out_w  = (const float*)d_in[13];
  const float* out_b  = (const float*)d_in[14];
  const float* temp   = (const float*)d_in[15];
  float* out = (float*)d_out;

  float* ws = (float*)d_ws;
  const size_t SP = (size_t)NB * NC * NTOK;   // 1,048,576
  float* attb = ws;                                        // SP f32 (4MB)
  unsigned* xph   = (unsigned*)(attb + SP);                // 512K u32 (2MB)
  unsigned* yph   = xph + 524288;                          // 512K u32 (2MB)
  unsigned* qh    = yph + 524288;                          // 512K u32 (2MB)
  unsigned* ktd   = qh + 524288;                           // 512K u32 (2MB)
  unsigned short* vbf = (unsigned short*)(ktd + 524288);   // SP ushorts (2MB)
  unsigned* wph   = (unsigned*)(vbf + SP);                 // 32768 u32 (128KB)

  k_prep<<<4224, 256, 0, stream>>>(x, y, q1_w, kv1_w, out_w, xph, yph, wph);
  k_qkv<<<768, 1024, 0, stream>>>(xph, yph, wph, q1_b, q2_w, q2_b,
                                  kv1_b, kv2_w, kv2_b, qh, ktd, vbf);
  k_attn<<<2048, 512, 0, stream>>>(qh, ktd, vbf, rel, temp, attb);
  k_midfinal<<<512, 256, 0, stream>>>(x, lepe_w, lepe_b, attb, wph, out_b, out);
}

// Round 21
// 153.128 us; speedup vs baseline: 1.3491x; 1.0200x over previous
//
#include <hip/hip_runtime.h>

// Problem constants
#define NB 8
#define NC 128
#define NH 64
#define NW 64
#define HEADS 4
#define HP 32
#define WP 32
#define NTOK 1024     // HP*WP
#define TOPK 32
#define HDIM 32

typedef __fp16 hh2 __attribute__((ext_vector_type(2)));
typedef __fp16 half8 __attribute__((ext_vector_type(8)));
typedef float v4f __attribute__((ext_vector_type(4)));

__device__ __forceinline__ hh2 h2cast(unsigned u) {
  union { unsigned u; hh2 h; } x; x.u = u; return x.h;
}
__device__ __forceinline__ unsigned pkf16(float a, float b) {
  union { hh2 h; unsigned u; } x; x.h = __builtin_amdgcn_cvt_pkrtz(a, b); return x.u;
}
__device__ __forceinline__ half8 h8cast(uint4 u) {
  union { uint4 u; half8 h; } x; x.u = u; return x.h;
}

#if __has_builtin(__builtin_amdgcn_fdot2)
__device__ __forceinline__ float fdot2(unsigned kw, unsigned qw, float c) {
  return __builtin_amdgcn_fdot2(h2cast(kw), h2cast(qw), c, false);
}
#else
__device__ __forceinline__ float fdot2(unsigned kw, unsigned qw, float c) {
  hh2 k = h2cast(kw), q = h2cast(qw);
  return fmaf((float)k.x, (float)q.x, fmaf((float)k.y, (float)q.y, c));
}
#endif

// monotone float->uint map (order-preserving) and inverse
__device__ __forceinline__ unsigned fmap(float f) {
  unsigned u = __float_as_uint(f);
  return u ^ ((unsigned)((int)u >> 31) | 0x80000000u);
}
__device__ __forceinline__ float funmap(unsigned k) {
  unsigned uo = k ^ ((unsigned)((int)(~k) >> 31) | 0x80000000u);
  return __uint_as_float(uo);
}

// DPP wave64 max-reduce on unsigned; result broadcast via readlane(63)
__device__ __forceinline__ unsigned wave_maxu(unsigned v) {
#define ST(ctrl)                                                                     \
  {                                                                                  \
    unsigned o = (unsigned)__builtin_amdgcn_update_dpp(0, (int)v, ctrl, 0xF, 0xF, true); \
    v = v > o ? v : o;                                                               \
  }
  ST(0xB1)   // quad_perm [1,0,3,2]
  ST(0x4E)   // quad_perm [2,3,0,1]
  ST(0x141)  // row_half_mirror
  ST(0x140)  // row_mirror
  ST(0x142)  // row_bcast:15
  ST(0x143)  // row_bcast:31
#undef ST
  return (unsigned)__builtin_amdgcn_readlane((int)v, 63);
}

// DPP wave64 float sum-reduce; result broadcast via readlane(63)
__device__ __forceinline__ float wave_sumf(float v) {
#define STA(ctrl)                                                                    \
  v += __int_as_float(__builtin_amdgcn_update_dpp(0, __float_as_int(v), ctrl, 0xF, 0xF, true));
  STA(0xB1)
  STA(0x4E)
  STA(0x141)
  STA(0x140)
  STA(0x142)
  STA(0x143)
#undef STA
  return __int_as_float(__builtin_amdgcn_readlane(__float_as_int(v), 63));
}

// DPP wave64 inclusive prefix-sum on unsigned. Safe for packed 16+16 fields.
__device__ __forceinline__ unsigned wave_iprefix(unsigned v, int lane) {
#define SH(ctrl)                                                                     \
  v += (unsigned)__builtin_amdgcn_update_dpp(0, (int)v, ctrl, 0xF, 0xF, true);
  SH(0x111)  // row_shr:1
  SH(0x112)  // row_shr:2
  SH(0x114)  // row_shr:4
  SH(0x118)  // row_shr:8
#undef SH
  unsigned r0 = (unsigned)__builtin_amdgcn_readlane((int)v, 15);
  unsigned r1 = (unsigned)__builtin_amdgcn_readlane((int)v, 31);
  unsigned r2 = (unsigned)__builtin_amdgcn_readlane((int)v, 47);
  v += (lane >= 16) ? r0 : 0u;
  v += (lane >= 32) ? r1 : 0u;
  v += (lane >= 48) ? r2 : 0u;
  return v;
}

// ---------------------------------------------------------------
// prep: avg-pool x,y -> f16 channel-pairs AND pack conv weights to f16 pairs.
__global__ void k_prep(const float* __restrict__ x, const float* __restrict__ y,
                       const float* __restrict__ q1w, const float* __restrict__ kv1w,
                       const float* __restrict__ outw,
                       unsigned* __restrict__ xph, unsigned* __restrict__ yph,
                       unsigned* __restrict__ wph) {
  int idx = blockIdx.x * 256 + threadIdx.x;
  const int total = NB * 64 * NTOK; // 524288 pairs per array
  if (idx < 2 * total) {
    bool isY = idx >= total;
    int i = isY ? idx - total : idx;
    int p = i & 1023;
    int pw = p & 31, ph = p >> 5;
    int bc2 = i >> 10;
    int c2 = bc2 & 63, b = bc2 >> 6;
    const float* s0 = (isY ? y : x) + (((size_t)b * NC + 2 * c2) * 64 + ph * 2) * 64 + pw * 2;
    const float* s1 = s0 + 4096;
    float v0 = 0.25f * (s0[0] + s0[1] + s0[64] + s0[65]);
    float v1 = 0.25f * (s1[0] + s1[1] + s1[64] + s1[65]);
    (isY ? yph : xph)[i] = pkf16(v0, v1);
  } else {
    int i = idx - 2 * total;
    if (i >= 32768) return;
    const float* src;
    int off;
    if (i < 8192) { src = q1w; off = i; }
    else if (i < 24576) { src = kv1w; off = i - 8192; }
    else { src = outw; off = i - 24576; }
    int co = off >> 6, ci2 = off & 63;
    wph[i] = pkf16(src[co * 128 + 2 * ci2], src[co * 128 + 2 * ci2 + 1]);
  }
}

// ---------------------------------------------------------------
// unified q/kv path: f16-dot2 1x1 conv (4 ch/thread) -> LDS tile -> 3x3
// (depthwise for q, grouped-2 for kv). K written TOKEN-MAJOR:
// ktd[((b*4+h)*1024+tok)*16 + d2]. grid = 8b x 96 units (32 q + 64 kv).
__launch_bounds__(1024, 2)
__global__ void k_qkv(const unsigned* __restrict__ xph, const unsigned* __restrict__ yph,
                      const unsigned* __restrict__ wph,
                      const float* __restrict__ q1b, const float* __restrict__ q2w,
                      const float* __restrict__ q2b,
                      const float* __restrict__ kv1b, const float* __restrict__ kv2w,
                      const float* __restrict__ kv2b,
                      unsigned* __restrict__ qh, unsigned* __restrict__ ktd,
                      unsigned short* __restrict__ vbf) {
  __shared__ float cls[4][1024];
  int px = threadIdx.x;
  int bid = blockIdx.x;
  int b = bid / 96;
  int u = bid - b * 96;
  bool isQ = u < 32;
  int q = isQ ? u : u - 32;

  const unsigned* ip = (isQ ? xph : yph) + (size_t)b * 64 * NTOK + px;
  const unsigned* wp = wph + (isQ ? 0 : 8192) + q * 4 * 64;
  const float* bb = isQ ? q1b : kv1b;
  float acc[4];
#pragma unroll
  for (int i = 0; i < 4; i++) acc[i] = bb[q * 4 + i];
  for (int ci2 = 0; ci2 < 64; ci2++) {
    unsigned mv = ip[ci2 * NTOK];
#pragma unroll
    for (int i = 0; i < 4; i++) acc[i] = fdot2(mv, wp[i * 64 + ci2], acc[i]);
  }
#pragma unroll
  for (int i = 0; i < 4; i++) cls[i][px] = acc[i];
  __syncthreads();
  int pw = px & 31, ph = px >> 5;

  if (isQ) {
    float aout[4];
#pragma unroll
    for (int i = 0; i < 4; i++) {
      int c = q * 4 + i;
      const float* wq = q2w + c * 9;
      float a = q2b[c];
#pragma unroll
      for (int ky = 0; ky < 3; ky++) {
        int ih = ph + ky - 1;
        if (ih < 0 || ih > 31) continue;
#pragma unroll
        for (int kx = 0; kx < 3; kx++) {
          int iw = pw + kx - 1;
          if (iw < 0 || iw > 31) continue;
          a = fmaf(wq[ky * 3 + kx], cls[i][ih * 32 + iw], a);
        }
      }
      aout[i] = a;
    }
    int h = q >> 3;
    int d2 = ((q * 4) & 31) >> 1;
    size_t base = (((size_t)b * HEADS + h) * NTOK + px) * 16;
    qh[base + d2] = pkf16(aout[0], aout[1]);
    qh[base + d2 + 1] = pkf16(aout[2], aout[3]);
  } else {
    float aout[4];
#pragma unroll
    for (int i = 0; i < 4; i++) {
      int o = q * 4 + i;       // kv channel 0..255
      int l0 = i & ~1;         // group's first input channel within the quad
      const float* wq = kv2w + o * 18; // [2][3][3]
      float a = kv2b[o];
#pragma unroll
      for (int ky = 0; ky < 3; ky++) {
        int ih = ph + ky - 1;
        if (ih < 0 || ih > 31) continue;
#pragma unroll
        for (int kx = 0; kx < 3; kx++) {
          int iw = pw + kx - 1;
          if (iw < 0 || iw > 31) continue;
          a = fmaf(wq[ky * 3 + kx], cls[l0][ih * 32 + iw], a);
          a = fmaf(wq[9 + ky * 3 + kx], cls[l0 + 1][ih * 32 + iw], a);
        }
      }
      aout[i] = a;
    }
    if (q < 32) {
      // K channels, token-major f16 pairs
      int h = q >> 3;
      int d2 = ((q * 4) & 31) >> 1;
      size_t base = (((size_t)b * HEADS + h) * NTOK + px) * 16;
      ktd[base + d2] = pkf16(aout[0], aout[1]);
      ktd[base + d2 + 1] = pkf16(aout[2], aout[3]);
    } else {
      // V channels
#pragma unroll
      for (int i = 0; i < 4; i++) {
        int c = q * 4 + i - 128;
        int h = c >> 5, d = c & 31;
        union { __fp16 h; unsigned short u; } cv;
        cv.h = (__fp16)aout[i];
        vbf[(((size_t)b * HEADS + h) * NTOK + px) * HDIM + d] = cv.u;
      }
    }
  }
}

// ---------------------------------------------------------------
// attention v15: MFMA QK^T -> raw scores to LDS S[16][1028] (pad 1028:
// 4*1028 % 32 == 16 -> row-groups split across bank halves, 2-way max = free).
// rel is added in the SELECT phase with fully-coalesced loads (token order
// e*64+lane), removing the scattered per-lane rel gathers from the MFMA phase.
// grid: 2048 = 64 tiles x 4 h x 8 b; block 512 (8 waves).
#define SPAD 1028
__launch_bounds__(512, 2)
__global__ void k_attn(const unsigned* __restrict__ qh, const unsigned* __restrict__ ktd,
                       const unsigned short* __restrict__ vbf, const float* __restrict__ rel,
                       const float* __restrict__ temp, float* __restrict__ att) {
  __shared__ float slds[16 * SPAD];               // tmpr * QK scores, 65.8KB
  __shared__ __align__(16) unsigned cbuf[8 * 64]; // per-wave 32x(key,token), 2KB

  int bid = blockIdx.x;
  int tile = bid & 63;
  int h = (bid >> 6) & 3;
  int b = bid >> 8;
  int tid = threadIdx.x;
  int lane = tid & 63;
  int wave = __builtin_amdgcn_readfirstlane(tid >> 6); // 0..7, uniform

  int bh = b * HEADS + h;
  int qbase = tile * 16;
  const float tmpr = temp[h];

  // ---- MFMA phase: this wave owns tokens [wave*128, wave*128+128) ----
  {
    const unsigned* qp = qh + ((size_t)bh * NTOK + qbase) * 16;
    uint4 aU = *(const uint4*)&qp[(lane & 15) * 16 + (lane >> 4) * 4];
    half8 aF = h8cast(aU);

    const unsigned* kt = ktd + (size_t)bh * NTOK * 16;

#pragma unroll
    for (int f = 0; f < 8; f++) {
      int tokl = f * 16 + (lane & 15); // token offset within this wave's 128
      uint4 bU = *(const uint4*)&kt[((size_t)(wave * 128 + tokl)) * 16 + (lane >> 4) * 4];
      half8 bF = h8cast(bU);
      v4f c = {0.f, 0.f, 0.f, 0.f};
      c = __builtin_amdgcn_mfma_f32_16x16x32_f16(aF, bF, c, 0, 0, 0);
      // C/D: col = lane&15 (token), row = (lane>>4)*4 + j
#pragma unroll
      for (int j = 0; j < 4; j++) {
        int row = (lane >> 4) * 4 + j;
        slds[row * SPAD + wave * 128 + tokl] = tmpr * c[j];
      }
    }
  }
  __syncthreads();

  const unsigned short* vb = vbf + (size_t)bh * NTOK * HDIM;
  int vlane = lane & 31;
  unsigned* row_lds = cbuf + wave * 64; // 32 entries x 8B, private per wave

  // ---- select phase: this wave owns rows 2*wave, 2*wave+1 ----
  // kk[e] = fmap(S[row][tok] + rel[row][tok]), tok = e*64+lane (coalesced rel)
  unsigned kk[2][16];
#pragma unroll
  for (int r = 0; r < 2; r++) {
    int row = 2 * wave + r;
    const float* sr = &slds[row * SPAD];
    const float* rp = rel + ((size_t)bh * NTOK + qbase + row) * NTOK;
#pragma unroll
    for (int e = 0; e < 16; e++) {
      kk[r][e] = fmap(sr[e * 64 + lane] + rp[e * 64 + lane]);
    }
  }

  // wave max per row (bsearch upper bound + softmax max)
  unsigned M[2];
#pragma unroll
  for (int r = 0; r < 2; r++) {
    unsigned mx = kk[r][0];
#pragma unroll
    for (int e = 1; e < 16; e++) mx = mx > kk[r][e] ? mx : kk[r][e];
    M[r] = wave_maxu(mx);
  }

  // early-exit binary search; cap 32 -> exact-tie fallback
  unsigned lo0 = 0u, hi0 = M[0], lo1 = 0u, hi1 = M[1];
  unsigned T0x = 0u, T1x = 0u;
  bool d0 = false, d1 = false;
#pragma unroll 1
  for (int it = 0; it < 32; it++) {
    if (d0 && d1) break;
    if (!d0) {
      unsigned mid = lo0 + ((hi0 - lo0) >> 1);
      int c = 0;
#pragma unroll
      for (int e = 0; e < 16; e++) c += (int)__popcll(__ballot(kk[0][e] > mid));
      if (c >= TOPK) lo0 = mid; else hi0 = mid;
      if (c == TOPK) { T0x = mid; d0 = true; }
    }
    if (!d1) {
      unsigned mid = lo1 + ((hi1 - lo1) >> 1);
      int c = 0;
#pragma unroll
      for (int e = 0; e < 16; e++) c += (int)__popcll(__ballot(kk[1][e] > mid));
      if (c >= TOPK) lo1 = mid; else hi1 = mid;
      if (c == TOPK) { T1x = mid; d1 = true; }
    }
  }
  unsigned T[2];
  T[0] = d0 ? T0x : hi0;
  T[1] = d1 ? T1x : hi1;

  // per-row: tie handling, compaction, softmax + V gather
#pragma unroll
  for (int r = 0; r < 2; r++) {
    unsigned gtc = 0, tq = 0;
#pragma unroll
    for (int e = 0; e < 16; e++) {
      gtc += (kk[r][e] > T[r]) ? 1u : 0u;
      tq += (kk[r][e] == T[r]) ? 1u : 0u;
    }
    unsigned packed = gtc | (tq << 16);
    unsigned incl = wave_iprefix(packed, lane);
    unsigned tot = (unsigned)__builtin_amdgcn_readlane((int)incl, 63);
    unsigned n_gt = tot & 0xFFFFu;
    unsigned tie_pfx = (incl >> 16) - tq;
    unsigned extras = (unsigned)TOPK - n_gt; // 0 on early-exit rows
    int el = (int)extras - (int)tie_pfx;
    el = el < 0 ? 0 : el;
    el = el > (int)tq ? (int)tq : el;
    unsigned sc = gtc + (unsigned)el;
    unsigned wbase = wave_iprefix(sc, lane) - sc;

    unsigned wp = wbase, tr = tie_pfx;
#pragma unroll
    for (int e = 0; e < 16; e++) {
      bool gt = kk[r][e] > T[r];
      bool eq = (kk[r][e] == T[r]);
      bool take = gt || (eq && (tr < extras));
      tr += eq ? 1u : 0u;
      if (take) {
        ((uint2*)row_lds)[wp] = make_uint2(kk[r][e], (unsigned)(e * 64 + lane));
        wp++;
      }
    }

    // parallel softmax over the 32 entries (lanes 0..31) + pipelined V gather
    uint2 ent = ((const uint2*)row_lds)[vlane];
    float fv = funmap(ent.x);
    float mv = funmap(M[r]);
    float e_ = __expf(fv - mv);
    e_ = (lane < TOPK) ? e_ : 0.f;
    float se = wave_sumf(e_);

    float oacc = 0.f;
#pragma unroll
    for (int t = 0; t < TOPK; t++) {
      float es = __int_as_float(__builtin_amdgcn_readlane(__float_as_int(e_), t));
      int tok = __builtin_amdgcn_readlane((int)ent.y, t);
      union { unsigned short u; __fp16 h; } cv;
      cv.u = vb[(size_t)tok * HDIM + vlane];
      oacc = fmaf(es, (float)cv.h, oacc);
    }

    if (lane < HDIM) {
      att[((size_t)b * NC + h * HDIM + lane) * NTOK + (qbase + 2 * wave + r)] = oacc / se;
    }
  }
}

// ---------------------------------------------------------------
// bilinear 2x upsample weights (jax scale_and_translate semantics)
__device__ __forceinline__ void bil(int i, int& j0, int& j1, float& wa, float& wb) {
  if (i & 1) {
    j0 = i >> 1; j1 = j0 + 1; wa = 0.75f; wb = 0.25f;
    if (j1 > 31) { j1 = 31; wa = 1.f; wb = 0.f; }
  } else {
    j0 = (i >> 1) - 1; j1 = j0 + 1; wa = 0.25f; wb = 0.75f;
    if (j0 < 0) { j0 = 0; wa = 0.f; wb = 1.f; }
  }
}

// ---------------------------------------------------------------
// fused mid+final: phase 1 computes lepe+upsample for all 128 channels of
// one 64-px output row into LDS (f16 pairs, padded [64][65]); phase 2 runs
// the final 1x1 conv (f16-dot2, scalar-hoisted weights) from LDS.
// grid: 512 = 8b x 64 rows; block 256.
__launch_bounds__(256, 4)
__global__ void k_midfinal(const float* __restrict__ x, const float* __restrict__ lepe_w,
                           const float* __restrict__ lepe_b, const float* __restrict__ attb,
                           const unsigned* __restrict__ wph, const float* __restrict__ outb,
                           float* __restrict__ out) {
  __shared__ unsigned mlds[64 * 65]; // [ci2][px], +1 pad -> 2-way banks (free)
  int bid = blockIdx.x;
  int h0 = bid & 63;
  int b = bid >> 6;
  int t = threadIdx.x;
  int ci2 = t >> 2;
  int w0 = (t & 3) * 16;

  int jh0, jh1;
  float wha, whb;
  bil(h0, jh0, jh1, wha, whb);

  float o0[16], o1[16];
#pragma unroll
  for (int cc = 0; cc < 2; cc++) {
    int c = 2 * ci2 + cc;
    const float* xp = x + ((size_t)b * NC + c) * 4096;
    const float* wq = lepe_w + c * 25;
    float* o = cc ? o1 : o0;
    float bv = lepe_b[c];
#pragma unroll
    for (int j = 0; j < 16; j++) o[j] = bv;
#pragma unroll
    for (int ky = 0; ky < 5; ky++) {
      int ih = h0 + ky - 2;
      if (ih < 0 || ih > 63) continue;
      float xr[20]; // sliding window [w0-2 .. w0+17]
#pragma unroll
      for (int m = 0; m < 20; m++) {
        int iw = w0 + m - 2;
        xr[m] = (iw >= 0 && iw <= 63) ? xp[ih * 64 + iw] : 0.f;
      }
#pragma unroll
      for (int kx = 0; kx < 5; kx++) {
        float wv = wq[ky * 5 + kx];
#pragma unroll
        for (int j = 0; j < 16; j++) o[j] = fmaf(wv, xr[j + kx], o[j]);
      }
    }
    // upsample add
    const float* ap = attb + ((size_t)b * NC + c) * NTOK;
#pragma unroll
    for (int j = 0; j < 16; j++) {
      int w = w0 + j;
      int jw0, jw1;
      float wwa, wwb;
      bil(w, jw0, jw1, wwa, wwb);
      float up = wha * (wwa * ap[jh0 * 32 + jw0] + wwb * ap[jh0 * 32 + jw1]) +
                 whb * (wwa * ap[jh1 * 32 + jw0] + wwb * ap[jh1 * 32 + jw1]);
      o[j] += up;
    }
  }
#pragma unroll
  for (int j = 0; j < 16; j++) mlds[ci2 * 65 + w0 + j] = pkf16(o0[j], o1[j]);
  __syncthreads();

  // phase 2: final 1x1, 32 outputs/thread
  int px = t & 63;
  int cg = __builtin_amdgcn_readfirstlane(t >> 6); // wave-uniform -> s_loads
  float acc[32];
#pragma unroll
  for (int i = 0; i < 32; i++) acc[i] = outb[cg * 32 + i];
  const unsigned* wpf = wph + 24576 + (size_t)cg * 32 * 64;
  for (int ci = 0; ci < 64; ci++) {
    unsigned mv = mlds[ci * 65 + px];
#pragma unroll
    for (int i = 0; i < 32; i++) acc[i] = fdot2(mv, wpf[i * 64 + ci], acc[i]);
  }
#pragma unroll
  for (int i = 0; i < 32; i++)
    out[((size_t)b * NC + cg * 32 + i) * 4096 + h0 * 64 + px] = acc[i];
}

// ---------------------------------------------------------------
extern "C" void kernel_launch(void* const* d_in, const int* in_sizes, int n_in,
                              void* d_out, int out_size, void* d_ws, size_t ws_size,
                              hipStream_t stream) {
  const float* x      = (const float*)d_in[0];
  const float* y      = (const float*)d_in[1];
  const float* rel    = (const float*)d_in[2];
  const float* q1_w   = (const float*)d_in[3];
  const float* q1_b   = (const float*)d_in[4];
  const float* q2_w   = (const float*)d_in[5];
  const float* q2_b   = (const float*)d_in[6];
  const float* kv1_w  = (const float*)d_in[7];
  const float* kv1_b  = (const float*)d_in[8];
  const float* kv2_w  = (const float*)d_in[9];
  const float* kv2_b  = (const float*)d_in[10];
  const float* lepe_w = (const float*)d_in[11];
  const float* lepe_b = (const float*)d_in[12];
  const float* out_w  = (const float*)d_in[13];
  const float* out_b  = (const float*)d_in[14];
  const float* temp   = (const float*)d_in[15];
  float* out = (float*)d_out;

  float* ws = (float*)d_ws;
  const size_t SP = (size_t)NB * NC * NTOK;   // 1,048,576
  float* attb = ws;                                        // SP f32 (4MB)
  unsigned* xph   = (unsigned*)(attb + SP);                // 512K u32 (2MB)
  unsigned* yph   = xph + 524288;                          // 512K u32 (2MB)
  unsigned* qh    = yph + 524288;                          // 512K u32 (2MB)
  unsigned* ktd   = qh + 524288;                           // 512K u32 (2MB)
  unsigned short* vbf = (unsigned short*)(ktd + 524288);   // SP ushorts (2MB)
  unsigned* wph   = (unsigned*)(vbf + SP);                 // 32768 u32 (128KB)

  k_prep<<<4224, 256, 0, stream>>>(x, y, q1_w, kv1_w, out_w, xph, yph, wph);
  k_qkv<<<768, 1024, 0, stream>>>(xph, yph, wph, q1_b, q2_w, q2_b,
                                  kv1_b, kv2_w, kv2_b, qh, ktd, vbf);
  k_attn<<<2048, 512, 0, stream>>>(qh, ktd, vbf, rel, temp, attb);
  k_midfinal<<<512, 256, 0, stream>>>(x, lepe_w, lepe_b, attb, wph, out_b, out);
}